// Round 1
// baseline (35.217 us; speedup 1.0000x reference)
//
#include <hip/hip_runtime.h>

#define DEV __device__ __forceinline__

namespace {

struct CF { float x, y; };

DEV CF cmul(CF a, float c, float s){ return {a.x*c - a.y*s, a.x*s + a.y*c}; }

DEV void halfsc(float th, float& c, float& s){
  float h = 0.5f*th;
  __sincosf(h, &s, &c);
}

constexpr float RSQRT2 = 0.70710678118654752440f;
constexpr float PI_F   = 3.14159265358979323846f;

// ---------------- circuit4 : 16 local amps, wire W <-> bit (3-W) ----------
template<int W> DEV void h4(CF (&a)[16]){
  constexpr int S = 8 >> W;
  #pragma unroll
  for (int m = 0; m < 16; ++m) if (!(m & S)) {
    CF u = a[m], v = a[m|S];
    a[m]   = {(u.x+v.x)*RSQRT2, (u.y+v.y)*RSQRT2};
    a[m|S] = {(u.x-v.x)*RSQRT2, (u.y-v.y)*RSQRT2};
  }
}
template<int W> DEV void rz4(CF (&a)[16], float th){
  constexpr int S = 8 >> W;
  float c, s; halfsc(th, c, s);
  #pragma unroll
  for (int m = 0; m < 16; ++m){
    float se = (m & S) ? s : -s;
    a[m] = cmul(a[m], c, se);
  }
}
template<int W> DEV void rx4(CF (&a)[16], float th){
  constexpr int S = 8 >> W;
  float c, s; halfsc(th, c, s);
  #pragma unroll
  for (int m = 0; m < 16; ++m) if (!(m & S)) {
    CF u = a[m], v = a[m|S];
    a[m]   = {c*u.x + s*v.y, c*u.y - s*v.x};
    a[m|S] = {c*v.x + s*u.y, c*v.y - s*u.x};
  }
}
template<int W> DEV void ry4(CF (&a)[16], float th){
  constexpr int S = 8 >> W;
  float c, s; halfsc(th, c, s);
  #pragma unroll
  for (int m = 0; m < 16; ++m) if (!(m & S)) {
    CF u = a[m], v = a[m|S];
    a[m]   = {c*u.x - s*v.x, c*u.y - s*v.y};
    a[m|S] = {s*u.x + c*v.x, s*u.y + c*v.y};
  }
}
template<int CW,int TW> DEV void crz4(CF (&a)[16], float th){
  constexpr int SC = 8 >> CW, ST = 8 >> TW;
  float c, s; halfsc(th, c, s);
  #pragma unroll
  for (int m = 0; m < 16; ++m) if (m & SC) {
    float se = (m & ST) ? s : -s;
    a[m] = cmul(a[m], c, se);
  }
}
template<int Q> DEV void enc4(CF (&a)[16], const float (&px)[16]){
  h4<Q>(a);
  rz4<Q>(a, px[Q*4+0]);
  rx4<Q>(a, px[Q*4+1]);
  rz4<Q>(a, px[Q*4+2]);
  rx4<Q>(a, px[Q*4+3]);
}

// ------------- circuit8 : 16 lanes/sample; wires 0..3 across lanes --------
// amp index A = b0<<7|..|b7 ; lane r = A>>4 (wires 0..3), local m = A&15.
template<int W> DEV bool bit8(int r, int m){
  if constexpr (W < 4) return ((r >> (3-W)) & 1) != 0;
  else                 return (m & (8 >> (W-4))) != 0;
}
template<int W> DEV void h8(CF (&a)[16], int r){
  if constexpr (W < 4) {
    constexpr int MASK = 8 >> W;
    float sg = bit8<W>(r, 0) ? -1.f : 1.f;
    #pragma unroll
    for (int m = 0; m < 16; ++m){
      float ox = __shfl_xor(a[m].x, MASK);
      float oy = __shfl_xor(a[m].y, MASK);
      a[m] = {(sg*a[m].x + ox)*RSQRT2, (sg*a[m].y + oy)*RSQRT2};
    }
  } else {
    constexpr int S = 8 >> (W-4);
    #pragma unroll
    for (int m = 0; m < 16; ++m) if (!(m & S)) {
      CF u = a[m], v = a[m|S];
      a[m]   = {(u.x+v.x)*RSQRT2, (u.y+v.y)*RSQRT2};
      a[m|S] = {(u.x-v.x)*RSQRT2, (u.y-v.y)*RSQRT2};
    }
  }
}
template<int W> DEV void rz8(CF (&a)[16], int r, float th){
  float c, s; halfsc(th, c, s);
  if constexpr (W < 4) {
    float se = bit8<W>(r,0) ? s : -s;
    #pragma unroll
    for (int m = 0; m < 16; ++m) a[m] = cmul(a[m], c, se);
  } else {
    #pragma unroll
    for (int m = 0; m < 16; ++m){
      float se = bit8<W>(r,m) ? s : -s;
      a[m] = cmul(a[m], c, se);
    }
  }
}
template<int W> DEV void rx8(CF (&a)[16], int r, float th){
  float c, s; halfsc(th, c, s);
  if constexpr (W < 4) {
    constexpr int MASK = 8 >> W;
    #pragma unroll
    for (int m = 0; m < 16; ++m){
      float ox = __shfl_xor(a[m].x, MASK);
      float oy = __shfl_xor(a[m].y, MASK);
      a[m] = {c*a[m].x + s*oy, c*a[m].y - s*ox};
    }
  } else {
    constexpr int S = 8 >> (W-4);
    #pragma unroll
    for (int m = 0; m < 16; ++m) if (!(m & S)) {
      CF u = a[m], v = a[m|S];
      a[m]   = {c*u.x + s*v.y, c*u.y - s*v.x};
      a[m|S] = {c*v.x + s*u.y, c*v.y - s*u.x};
    }
  }
}
template<int W> DEV void ry8(CF (&a)[16], int r, float th){
  float c, s; halfsc(th, c, s);
  if constexpr (W < 4) {
    constexpr int MASK = 8 >> W;
    float sg = bit8<W>(r,0) ? s : -s;   // bit0: c*mine - s*other ; bit1: +
    #pragma unroll
    for (int m = 0; m < 16; ++m){
      float ox = __shfl_xor(a[m].x, MASK);
      float oy = __shfl_xor(a[m].y, MASK);
      a[m] = {c*a[m].x + sg*ox, c*a[m].y + sg*oy};
    }
  } else {
    constexpr int S = 8 >> (W-4);
    #pragma unroll
    for (int m = 0; m < 16; ++m) if (!(m & S)) {
      CF u = a[m], v = a[m|S];
      a[m]   = {c*u.x - s*v.x, c*u.y - s*v.y};
      a[m|S] = {s*u.x + c*v.x, s*u.y + c*v.y};
    }
  }
}
template<int CW,int TW> DEV void crz8(CF (&a)[16], int r, float th){
  float c, s; halfsc(th, c, s);
  #pragma unroll
  for (int m = 0; m < 16; ++m){
    bool cb = bit8<CW>(r, m);
    bool tb = bit8<TW>(r, m);
    if (cb) a[m] = cmul(a[m], c, tb ? s : -s);
  }
}
template<int Q> DEV void enc8(CF (&a)[16], int r, const float* f){
  h8<Q>(a, r);
  #pragma unroll
  for (int i = 0; i < 9; ++i){
    const int idx = Q*9 + i;
    if (idx < 64) {                       // folds at compile time after unroll
      float th = PI_F * f[idx];
      if ((i & 1) == 0) rz8<Q>(a, r, th);
      else              rx8<Q>(a, r, th);
    }
  }
}

} // namespace

__global__ __launch_bounds__(512)
void qnn_fused_kernel(const float* __restrict__ X,  const float* __restrict__ w1,
                      const float* __restrict__ w2, const float* __restrict__ fcw,
                      const float* __restrict__ fcb, float* __restrict__ out, int bs)
{
  __shared__ float feats[32][65];           // +1 pad: conflict-free group reads
  const int t  = threadIdx.x;
  const int sl = t >> 4;                    // local sample 0..31
  const int r  = t & 15;                    // role == patch index in phase 1
  int sample = blockIdx.x * 32 + sl;
  if (sample >= bs) sample = bs - 1;        // duplicate work, keep barriers uniform

  // ---------------- phase 1: one 4-qubit circuit (patch r) per thread ------
  {
    const int pi = r >> 2, pj = r & 3;
    const int i0 = pi*4, j0 = pj*4;
    const float* xs = X + (size_t)sample * 196;
    float px[16];
    #pragma unroll
    for (int k = 0; k < 16; ++k) px[k] = 0.f;  // pad: RZ(0)/RX(0) == identity
    if (pi < 3 && pj < 3) {                    // 4x4 interior
      #pragma unroll
      for (int rr = 0; rr < 4; ++rr)
        #pragma unroll
        for (int cc = 0; cc < 4; ++cc)
          px[rr*4+cc] = xs[(i0+rr)*14 + j0 + cc];
    } else if (pi == 3 && pj < 3) {            // 2 rows x 4 cols
      #pragma unroll
      for (int rr = 0; rr < 2; ++rr)
        #pragma unroll
        for (int cc = 0; cc < 4; ++cc)
          px[rr*4+cc] = xs[(12+rr)*14 + j0 + cc];
    } else if (pi < 3) {                       // 4 rows x 2 cols
      #pragma unroll
      for (int rr = 0; rr < 4; ++rr)
        #pragma unroll
        for (int cc = 0; cc < 2; ++cc)
          px[rr*2+cc] = xs[(i0+rr)*14 + 12 + cc];
    } else {                                   // 2 x 2 corner
      #pragma unroll
      for (int rr = 0; rr < 2; ++rr)
        #pragma unroll
        for (int cc = 0; cc < 2; ++cc)
          px[rr*2+cc] = xs[(12+rr)*14 + 12 + cc];
    }

    CF a[16];
    #pragma unroll
    for (int m = 0; m < 16; ++m) a[m] = {0.f, 0.f};
    a[0] = {1.f, 0.f};
    enc4<0>(a, px); enc4<1>(a, px); enc4<2>(a, px); enc4<3>(a, px);
    #pragma unroll
    for (int l = 0; l < 2; ++l){
      const float* wl = w1 + l*8;
      crz4<0,1>(a, wl[0]); crz4<1,2>(a, wl[1]);
      crz4<2,3>(a, wl[2]); crz4<3,0>(a, wl[3]);
      ry4<0>(a, wl[4]); ry4<1>(a, wl[5]); ry4<2>(a, wl[6]); ry4<3>(a, wl[7]);
    }
    float pr[16];
    #pragma unroll
    for (int m = 0; m < 16; ++m) pr[m] = a[m].x*a[m].x + a[m].y*a[m].y;
    #pragma unroll
    for (int w = 0; w < 4; ++w){
      const int S = 8 >> w;
      float e = 0.f;
      #pragma unroll
      for (int m = 0; m < 16; ++m) e += (m & S) ? -pr[m] : pr[m];
      feats[sl][r*4 + w] = e;
    }
  }
  __syncthreads();

  // ---------------- phase 2: 8-qubit circuit, 16 lanes cooperate -----------
  const float* f = feats[sl];
  CF a[16];
  #pragma unroll
  for (int m = 0; m < 16; ++m) a[m] = {0.f, 0.f};
  if (r == 0) a[0] = {1.f, 0.f};
  enc8<0>(a, r, f); enc8<1>(a, r, f); enc8<2>(a, r, f); enc8<3>(a, r, f);
  enc8<4>(a, r, f); enc8<5>(a, r, f); enc8<6>(a, r, f); enc8<7>(a, r, f);
  #pragma unroll
  for (int l = 0; l < 3; ++l){
    const float* wl = w2 + l*16;
    crz8<0,1>(a, r, wl[0]); crz8<1,2>(a, r, wl[1]);
    crz8<2,3>(a, r, wl[2]); crz8<3,4>(a, r, wl[3]);
    crz8<4,5>(a, r, wl[4]); crz8<5,6>(a, r, wl[5]);
    crz8<6,7>(a, r, wl[6]); crz8<7,0>(a, r, wl[7]);
    ry8<0>(a, r, wl[8]);  ry8<1>(a, r, wl[9]);
    ry8<2>(a, r, wl[10]); ry8<3>(a, r, wl[11]);
    ry8<4>(a, r, wl[12]); ry8<5>(a, r, wl[13]);
    ry8<6>(a, r, wl[14]); ry8<7>(a, r, wl[15]);
  }
  float pr[16];
  #pragma unroll
  for (int m = 0; m < 16; ++m) pr[m] = a[m].x*a[m].x + a[m].y*a[m].y;
  float Ssum = 0.f;
  #pragma unroll
  for (int m = 0; m < 16; ++m) Ssum += pr[m];
  float g[8];
  g[0] = ((r >> 3) & 1) ? -Ssum : Ssum;
  g[1] = ((r >> 2) & 1) ? -Ssum : Ssum;
  g[2] = ((r >> 1) & 1) ? -Ssum : Ssum;
  g[3] = ( r       & 1) ? -Ssum : Ssum;
  #pragma unroll
  for (int w = 4; w < 8; ++w){
    const int St = 8 >> (w-4);
    float e = 0.f;
    #pragma unroll
    for (int m = 0; m < 16; ++m) e += (m & St) ? -pr[m] : pr[m];
    g[w] = e;
  }
  #pragma unroll
  for (int mask = 1; mask <= 8; mask <<= 1){
    #pragma unroll
    for (int w = 0; w < 8; ++w) g[w] += __shfl_xor(g[w], mask);
  }
  if (r < 3){
    float o = fcb[r];
    #pragma unroll
    for (int w = 0; w < 8; ++w) o += fcw[r*8 + w] * g[w];
    out[(size_t)sample*3 + r] = o;
  }
}

extern "C" void kernel_launch(void* const* d_in, const int* in_sizes, int n_in,
                              void* d_out, int out_size, void* d_ws, size_t ws_size,
                              hipStream_t stream)
{
  const float* X   = (const float*)d_in[0];
  const float* w1  = (const float*)d_in[1];
  const float* w2  = (const float*)d_in[2];
  const float* fcw = (const float*)d_in[3];
  const float* fcb = (const float*)d_in[4];
  float* out = (float*)d_out;
  const int bs = in_sizes[0] / 196;            // 8192
  const int blocks = (bs + 31) / 32;           // 32 samples / block
  hipLaunchKernelGGL(qnn_fused_kernel, dim3(blocks), dim3(512), 0, stream,
                     X, w1, w2, fcw, fcb, out, bs);
}